// Round 7
// baseline (12919.284 us; speedup 1.0000x reference)
//
#include <hip/hip_runtime.h>
#include <math.h>

#define BATCH 256
#define TSTEPS 256
#define DIN 128
#define HID 256
#define GATES 1024
#define NOUT 64

#define NGROUP 8
#define MB 32
#define NJB 32
#define NJ 8
#define NTHR 256

#define HS_OFF 0ull
#define HS_SZ  ((unsigned long long)(TSTEPS+1)*BATCH*HID)
#define BMIX_OFF HS_SZ
#define COEF_OFF (BMIX_OFF + (unsigned long long)TSTEPS*GATES)
#define FLAG_OFF (COEF_OFF + 2ull*TSTEPS)

// ---------------- prep: softmax coef, premixed bias, zero h0 and flags ----------------
__global__ void prep_kernel(const float* __restrict__ alpha,
                            const float* __restrict__ bvec,
                            float* __restrict__ wsf) {
  unsigned idx = blockIdx.x * blockDim.x + threadIdx.x;
  if (idx < (unsigned)(TSTEPS * GATES)) {
    int t = idx >> 10, col = idx & (GATES - 1);
    float a0 = alpha[2 * t], a1 = alpha[2 * t + 1];
    float m = fmaxf(a0, a1);
    float e0 = expf(a0 - m), e1 = expf(a1 - m);
    float inv = 1.f / (e0 + e1);
    wsf[BMIX_OFF + idx] = (e0 * inv) * bvec[col] + (e1 * inv) * bvec[GATES + col];
  }
  if (idx < (unsigned)(BATCH * HID)) wsf[HS_OFF + idx] = 0.f;
  if (idx < (unsigned)(2 * TSTEPS)) {
    int t = idx >> 1;
    float a0 = alpha[2 * t], a1 = alpha[2 * t + 1];
    float m = fmaxf(a0, a1);
    float e0 = expf(a0 - m), e1 = expf(a1 - m);
    float inv = 1.f / (e0 + e1);
    wsf[COEF_OFF + idx] = ((idx & 1) ? e1 : e0) * inv;
  }
  if (idx < (unsigned)(TSTEPS * NGROUP * NJB)) {
    ((unsigned*)(wsf + FLAG_OFF))[idx] = 0u;
  }
}

// ---------------- cooperative recurrent kernel ----------------
// 256 blocks = 8 batch-groups (32 rows each) x 32 j-blocks (8 hidden units each).
// group = blockIdx%8 so a group's 32 blocks share an XCD (perf only).
// Each thread owns one (batch-row, hidden-unit): 4 gate dots + LSTM cell, c in a register.
__global__ void __launch_bounds__(NTHR, 1) lstm_coop(const float* __restrict__ x,
                                                     const float* __restrict__ Wih,
                                                     const float* __restrict__ Whh,
                                                     float* __restrict__ wsf) {
  __shared__ float4 s_wmix[2][32 * NJ];     // premixed weight chunk [k 0..31][j 0..7][gate 0..3], dbuf
  __shared__ float s_h[MB][HID + 4];        // 32 x 260 (pad: conflict-free dot reads)
  __shared__ float s_x[MB][DIN + 4];        // 32 x 132

  const int tid = threadIdx.x;
  const int bid = blockIdx.x;
  const int grp = bid & (NGROUP - 1);
  const int jb  = bid >> 3;
  const int b0  = grp * MB;
  const int j0  = jb * NJ;
  const int bloc = tid >> 3;   // 0..31 : batch row (also premix k_local)
  const int jj   = tid & 7;    // 0..7  : hidden unit within slice
  const int jcol = j0 + jj;

  float* hs = wsf + HS_OFF;
  const float* bmix = wsf + BMIX_OFF;
  const float* coef = wsf + COEF_OFF;
  unsigned* flags = (unsigned*)(wsf + FLAG_OFF);

  // per-thread premix source bases: element (k_local=bloc, col jcol, gate g at +g*256)
  const float* whhT = Whh + bloc * GATES + jcol;
  const float* wihT = Wih + bloc * GATES + jcol;

  float c_state = 0.f;

  for (int t = 0; t < TSTEPS; ++t) {
    // ---- x tile fill (issued before the barrier poll to hide latency) ----
    {
      const float* xr = x + ((size_t)(b0 + bloc) * TSTEPS + t) * DIN + jj * 16;
      float* xd = &s_x[bloc][jj * 16];
      #pragma unroll
      for (int i = 0; i < 4; ++i)
        *reinterpret_cast<float4*>(xd + i * 4) = *reinterpret_cast<const float4*>(xr + i * 4);
    }
    // ---- wait for previous step's h from all 32 j-blocks of this group ----
    if (t > 0) {
      if (tid < 64) {
        unsigned* fl = flags + (size_t)(t - 1) * (NGROUP * NJB) + grp * NJB;
        for (;;) {
          unsigned v = (tid < NJB)
            ? __hip_atomic_load(fl + tid, __ATOMIC_ACQUIRE, __HIP_MEMORY_SCOPE_AGENT)
            : 1u;
          if (__all(v != 0u)) break;
          __builtin_amdgcn_s_sleep(1);
        }
      }
      __syncthreads();
      __threadfence();   // acquire: invalidate caches before reading peer h
    }
    // ---- h tile fill ----
    {
      const float* hr = hs + (size_t)t * BATCH * HID + (size_t)(b0 + bloc) * HID + jj * 32;
      float* hd = &s_h[bloc][jj * 32];
      #pragma unroll
      for (int i = 0; i < 8; ++i)
        *reinterpret_cast<float4*>(hd + i * 4) = *reinterpret_cast<const float4*>(hr + i * 4);
    }

    const float c0 = coef[2 * t], c1 = coef[2 * t + 1];
    float acc0 = 0.f, acc1 = 0.f, acc2 = 0.f, acc3 = 0.f;
    float r0[4], r1[4];
    {
      const float* p0 = whhT;
      const float* p1 = whhT + HID * GATES;
      #pragma unroll
      for (int u = 0; u < 4; ++u) { r0[u] = p0[u * 256]; r1[u] = p1[u * 256]; }
    }
    const float* hrow = &s_h[bloc][0];
    const float* xrow = &s_x[bloc][0];

    // 12 K-chunks of 32: chunks 0..7 = h (H=256), 8..11 = x (D=128)
    for (int cc = 0; cc < 12; ++cc) {
      float4 wv;
      wv.x = c0 * r0[0] + c1 * r1[0];
      wv.y = c0 * r0[1] + c1 * r1[1];
      wv.z = c0 * r0[2] + c1 * r1[2];
      wv.w = c0 * r0[3] + c1 * r1[3];
      s_wmix[cc & 1][bloc * NJ + jj] = wv;
      int cn = cc + 1;
      if (cn < 12) {  // prefetch next chunk's raw weights (overlaps dot below)
        const float* p0 = (cn < 8) ? (whhT + cn * 32 * GATES) : (wihT + (cn - 8) * 32 * GATES);
        const float* p1 = p0 + ((cn < 8) ? HID * GATES : DIN * GATES);
        #pragma unroll
        for (int u = 0; u < 4; ++u) { r0[u] = p0[u * 256]; r1[u] = p1[u * 256]; }
      }
      __syncthreads();
      const float4* wm = s_wmix[cc & 1];
      const float* hb = (cc < 8) ? (hrow + cc * 32) : (xrow + (cc - 8) * 32);
      #pragma unroll
      for (int k4 = 0; k4 < 8; ++k4) {
        float4 hv = *reinterpret_cast<const float4*>(hb + k4 * 4);
        float4 w;
        w = wm[(k4 * 4 + 0) * NJ + jj];
        acc0 += hv.x * w.x; acc1 += hv.x * w.y; acc2 += hv.x * w.z; acc3 += hv.x * w.w;
        w = wm[(k4 * 4 + 1) * NJ + jj];
        acc0 += hv.y * w.x; acc1 += hv.y * w.y; acc2 += hv.y * w.z; acc3 += hv.y * w.w;
        w = wm[(k4 * 4 + 2) * NJ + jj];
        acc0 += hv.z * w.x; acc1 += hv.z * w.y; acc2 += hv.z * w.z; acc3 += hv.z * w.w;
        w = wm[(k4 * 4 + 3) * NJ + jj];
        acc0 += hv.w * w.x; acc1 += hv.w * w.y; acc2 += hv.w * w.z; acc3 += hv.w * w.w;
      }
    }

    // ---- LSTM cell ----
    const float* bm = bmix + (size_t)t * GATES + jcol;
    float pi = acc0 + bm[0];
    float pf = acc1 + bm[256];
    float pg = acc2 + bm[512];
    float po = acc3 + bm[768];
    float iv = 1.f / (1.f + expf(-pi));
    float fv = 1.f / (1.f + expf(-pf));
    float gv = tanhf(pg);
    float ov = 1.f / (1.f + expf(-po));
    c_state = fv * c_state + iv * gv;
    float hv = ov * tanhf(c_state);
    hs[(size_t)(t + 1) * BATCH * HID + (size_t)(b0 + bloc) * HID + jcol] = hv;
    __threadfence();     // make this thread's h store agent-visible
    __syncthreads();     // all block stores+fences done
    if (tid == 0)
      __hip_atomic_store(&flags[(size_t)t * (NGROUP * NJB) + grp * NJB + jb], 1u,
                         __ATOMIC_RELEASE, __HIP_MEMORY_SCOPE_AGENT);
  }
}

// ---------------- output projection: out[b,t,:] = hs[t+1,b,:] @ W_out + b_out ----------------
__global__ void __launch_bounds__(256) out_kernel(const float* __restrict__ wsf,
                                                  const float* __restrict__ Wout,
                                                  const float* __restrict__ bout,
                                                  float* __restrict__ outp) {
  __shared__ float s_ht[HID][MB];   // transposed h tile: conflict-free reads
  __shared__ float s_wo[HID][32];
  const int tid = threadIdx.x;
  const int rb = blockIdx.x;   // 0..2047 (32 hs-rows each)
  const int cb = blockIdx.y;   // 0..1 (column half)
  const float* hs1 = wsf + HS_OFF + (size_t)BATCH * HID;  // hs_full[1]
  const int ri0 = rb * MB;
  {
    const int r = tid & 31, kq = tid >> 5;
    const float* hr = hs1 + (size_t)(ri0 + r) * HID + kq * 32;
    #pragma unroll
    for (int i = 0; i < 8; ++i) {
      float4 v = *reinterpret_cast<const float4*>(hr + i * 4);
      int k = kq * 32 + i * 4;
      s_ht[k + 0][r] = v.x; s_ht[k + 1][r] = v.y; s_ht[k + 2][r] = v.z; s_ht[k + 3][r] = v.w;
    }
  }
  {
    #pragma unroll
    for (int i = 0; i < 32; ++i) {
      int e = i * 256 + tid;
      int k = e >> 5, o = e & 31;
      s_wo[k][o] = Wout[k * NOUT + cb * 32 + o];
    }
  }
  __syncthreads();
  const int row = tid >> 3, oq = tid & 7;
  float4 acc = *reinterpret_cast<const float4*>(bout + cb * 32 + oq * 4);
  #pragma unroll 4
  for (int k = 0; k < HID; ++k) {
    float hv = s_ht[k][row];
    float4 w = *reinterpret_cast<const float4*>(&s_wo[k][oq * 4]);
    acc.x += hv * w.x; acc.y += hv * w.y; acc.z += hv * w.z; acc.w += hv * w.w;
  }
  const int ri = ri0 + row;
  const int tt = ri >> 8, bb = ri & 255;
  *reinterpret_cast<float4*>(outp + ((size_t)bb * TSTEPS + tt) * NOUT + cb * 32 + oq * 4) = acc;
}

extern "C" void kernel_launch(void* const* d_in, const int* in_sizes, int n_in,
                              void* d_out, int out_size, void* d_ws, size_t ws_size,
                              hipStream_t stream) {
  const float* x     = (const float*)d_in[0];
  const float* Wih   = (const float*)d_in[1];
  const float* Whh   = (const float*)d_in[2];
  const float* bvec  = (const float*)d_in[3];
  const float* alpha = (const float*)d_in[4];
  const float* Wout  = (const float*)d_in[5];
  const float* bout  = (const float*)d_in[6];
  float* outp = (float*)d_out;
  float* wsf  = (float*)d_ws;

  prep_kernel<<<dim3((TSTEPS * GATES + 255) / 256), dim3(256), 0, stream>>>(alpha, bvec, wsf);

  void* args[] = { (void*)&x, (void*)&Wih, (void*)&Whh, (void*)&wsf };
  hipError_t err = hipLaunchCooperativeKernel((void*)lstm_coop, dim3(NGROUP * NJB), dim3(NTHR),
                                              args, 0, stream);
  if (err != hipSuccess) {
    // fallback: 256 blocks <= min co-resident capacity (58KB LDS -> 2 blocks/CU), safe in practice
    lstm_coop<<<dim3(NGROUP * NJB), dim3(NTHR), 0, stream>>>(x, Wih, Whh, wsf);
  }

  out_kernel<<<dim3((BATCH * TSTEPS) / MB, 2), dim3(256), 0, stream>>>(wsf, Wout, bout, outp);
}